// Round 15
// baseline (101.901 us; speedup 1.0000x reference)
//
#include <hip/hip_runtime.h>
#include <stdint.h>

typedef float f32x4 __attribute__((ext_vector_type(4)));
typedef __bf16 bf16x8 __attribute__((ext_vector_type(8)));
typedef __bf16 bf16x4 __attribute__((ext_vector_type(4)));

#define NROWS 65536     // 16 * 4096 x-rows
#define NCODES 4096
#define NDIM 64
#define STEPS 128       // 4096 codes / 32 codes per step (full sweep per block)
#define SSTEP 2         // steps per barrier phase
#define PHASES (STEPS / SSTEP)  // 64
#define BIAS 2048.0f    // all T' = dot - c^2/2 - BIAS are < 0 (|dot| <= ~120)
#define CBMASK 0x7FFFF  // wrap within the 512KB codebook (rotation)

// ws layout (bytes):
//   [0x000000, 0x080000): codes bf16        4096*64*2 = 512 KB
//   [0x080000, 0x084000): nc2p paired (-||c||^2/2 - BIAS): float2[2048]
//       pair index = step*16 + col (step=code>>5) ; .x = col, .y = col+16

__device__ __forceinline__ void gld_lds16(const void* g, void* l) {
  __builtin_amdgcn_global_load_lds(
      (const __attribute__((address_space(1))) unsigned int*)g,
      (__attribute__((address_space(3))) unsigned int*)l, 16, 0, 0);
}

__device__ __forceinline__ uint32_t umin2(uint32_t a, uint32_t b) {
  return a < b ? a : b;
}

// Coalesced prep: 65536 threads, one f32x4 each; 16 lanes per code row.
// Writes bf16 codebook + paired (-||c||^2/2 - BIAS) layout (see ws map).
__global__ __launch_bounds__(256) void prep_codes_k(const float* __restrict__ codes,
                                                    float* __restrict__ nc2p,
                                                    __bf16* __restrict__ cb) {
  const int t = blockIdx.x * 256 + threadIdx.x;  // 0..65535
  f32x4 v = *(const f32x4*)(codes + t * 4);
  bf16x4 o;
  float s = 0.f;
#pragma unroll
  for (int j = 0; j < 4; j++) {
    o[j] = (__bf16)v[j];
    s += v[j] * v[j];
  }
  *(bf16x4*)(cb + t * 4) = o;
  s += __shfl_xor(s, 1);
  s += __shfl_xor(s, 2);
  s += __shfl_xor(s, 4);
  s += __shfl_xor(s, 8);
  if ((threadIdx.x & 15) == 0) {
    const int c = t >> 4;  // code id 0..4095
    const int pidx = (c >> 5) * 16 + (c & 15);  // step*16 + col
    const int half = (c >> 4) & 1;
    nc2p[pidx * 2 + half] = -0.5f * s - BIAS;
  }
}

// 8-WAVE REBALANCE (r14 fixed): 512 blocks x 512 threads (8 waves); each wave
// owns 16 rows (4 MFMA + ~12 merge-VALU per step, half of r13's per-wave
// chain), 16 waves/CU. Each block sweeps ALL 4096 codes (128 steps, 64 dbuf
// phases). STAGING FIX vs r14: ONE gld_lds per thread covers a full 8KB phase
// (wave w -> phase bytes [w*1024,(w+1)*1024), dest stage+w*1024; schunk=tid*16
// spans 8KB). Rotation is 8KB-GRANULAR (s0=(bid&63)*2) so maskedphasebase +
// schunk(<=8191) stays inside the 512KB codebook. r14's two-gld version
// overflowed the stage buffer and overwrote ncl -> absmax 4001.
// u32-key argmax (r11-verified): C-init = -c^2/2-2048 < 0 -> unsigned bit
// order = descending float order; key=(bits&0xFFFFF000)|code12; umin==argmax,
// lowest-code tie-break; merge via v_min3_u32. Truncation <=1.0 on T vs ~70
// threshold margin. Swizzle involution (rule #21): LDS[P]=G[P^(((P>>7)&7)<<4)]
// on store (P=tid*16), reader XORs the same (formula uses only addr bits 4-9,
// consistent across both 4KB tiles). A-frag: lane holds A[m=lane&15][k=quad*8+j].
// C/D: col(n)=lane&15, row(m)=quad*4+reg (m89/m91-verified).
__global__ __launch_bounds__(512, 4) void nn_main(const float* __restrict__ x,
                                                  const __bf16* __restrict__ cbv,
                                                  const float2* __restrict__ nc2p,
                                                  int* __restrict__ out) {
  const int tid  = threadIdx.x;            // 0..511
  const int lane = tid & 63;
  const int w    = tid >> 6;               // wave id 0..7
  const int col  = lane & 15;
  const int quad = lane >> 4;
  const int bid  = blockIdx.x;             // 0..511
  const int rowbase = bid * 128 + w * 16;
  const int s0 = (bid & 63) * 2;           // 8KB-granular rotation start step
  const char* cbb = (const char*)cbv;

  __shared__ __align__(16) char stage[2][SSTEP * 4096];  // 16 KB
  __shared__ __align__(8) float2 ncl[2048];              // 16 KB: [step][col]

  // ---- stage all nc2 pairs (16 KB, 2 glds/thread) + rotated phase 0 ----
  const uint32_t schunk = ((uint32_t)(tid * 16)) ^ ((((uint32_t)tid >> 3) & 7u) << 4);
  const char* srcbase = cbb + schunk;
  const uint32_t rot = (uint32_t)s0 * 4096u;  // multiple of 8192
#pragma unroll
  for (int i = 0; i < 2; i++)
    gld_lds16((const char*)nc2p + i * 8192 + w * 1024 + lane * 16,
              (char*)ncl + i * 8192 + w * 1024);
  // phase 0: one gld per thread; wave w covers bytes [w*1024,(w+1)*1024)
  gld_lds16(srcbase + rot, &stage[0][w * 1024]);

  // ---- A fragments (fp32 -> bf16) + ||x||^2 (overlaps with stages) ----
  bf16x8 a[2];
  float x2part;
  {
    const float* xr = x + (rowbase + col) * NDIM + quad * 8;
    float p = 0.f;
#pragma unroll
    for (int kc = 0; kc < 2; kc++) {
      f32x4 v0 = *(const f32x4*)(xr + kc * 32);
      f32x4 v1 = *(const f32x4*)(xr + kc * 32 + 4);
      bf16x8 af;
#pragma unroll
      for (int j = 0; j < 4; j++) {
        af[j]     = (__bf16)v0[j];
        af[j + 4] = (__bf16)v1[j];
        p += v0[j] * v0[j] + v1[j] * v1[j];
      }
      a[kc] = af;
    }
    p += __shfl_xor(p, 16);
    p += __shfl_xor(p, 32);
    x2part = p;  // every lane: x2 of row (rowbase + col)
  }

  uint32_t bestK[4];
#pragma unroll
  for (int j = 0; j < 4; j++) bestK[j] = 0xFFFFFFFFu;

  // ---- reader LDS byte offsets (swizzled), within a 4KB tile ----
  const uint32_t swz = ((uint32_t)(col & 7)) << 4;
  const uint32_t o00 = ((uint32_t)(col * 128 + quad * 16)) ^ swz;
  const uint32_t o01 = ((uint32_t)(col * 128 + 64 + quad * 16)) ^ swz;
  const uint32_t o10 = ((uint32_t)(2048 + col * 128 + quad * 16)) ^ swz;
  const uint32_t o11 = ((uint32_t)(2048 + col * 128 + 64 + quad * 16)) ^ swz;

  __syncthreads();  // ncl + phase 0 staged

#pragma unroll 1
  for (int p = 0; p < PHASES; ++p) {
    // prefetch next phase (one gld/thread; 8KB-aligned base, wrap in bounds:
    // (pb & CBMASK) <= 0x7E000, + schunk <= 0x7FFFF)
    if (p < PHASES - 1) {
      const uint32_t pb = (rot + (uint32_t)(p + 1) * 8192u) & CBMASK;
      gld_lds16(srcbase + pb, &stage[(p + 1) & 1][w * 1024]);
    }
    const char* sb = stage[p & 1];
#pragma unroll
    for (int ss = 0; ss < SSTEP; ss++) {
      const int s_eff = (s0 + p * SSTEP + ss) & 127;  // rotated step 0..127
      const float2 nv = ncl[s_eff * 16 + col];
      bf16x8 b00 = *(const bf16x8*)(sb + ss * 4096 + o00);
      bf16x8 b01 = *(const bf16x8*)(sb + ss * 4096 + o01);
      bf16x8 b10 = *(const bf16x8*)(sb + ss * 4096 + o10);
      bf16x8 b11 = *(const bf16x8*)(sb + ss * 4096 + o11);
      f32x4 ci0 = {nv.x, nv.x, nv.x, nv.x};
      f32x4 ci1 = {nv.y, nv.y, nv.y, nv.y};
      // code-id payloads (low 12 bits of key); s_eff<<5 uniform -> SALU
      const uint32_t vk0 = (uint32_t)(col | (s_eff << 5));
      const uint32_t vk1 = vk0 | 16u;
      f32x4 acc0 = __builtin_amdgcn_mfma_f32_16x16x32_bf16(a[0], b00, ci0, 0, 0, 0);
      acc0 = __builtin_amdgcn_mfma_f32_16x16x32_bf16(a[1], b01, acc0, 0, 0, 0);
      f32x4 acc1 = __builtin_amdgcn_mfma_f32_16x16x32_bf16(a[0], b10, ci1, 0, 0, 0);
      acc1 = __builtin_amdgcn_mfma_f32_16x16x32_bf16(a[1], b11, acc1, 0, 0, 0);
#pragma unroll
      for (int j = 0; j < 4; j++) {
        const uint32_t k0 = (__builtin_bit_cast(uint32_t, acc0[j]) & 0xFFFFF000u) | vk0;
        const uint32_t k1 = (__builtin_bit_cast(uint32_t, acc1[j]) & 0xFFFFF000u) | vk1;
        bestK[j] = umin2(bestK[j], umin2(k0, k1));  // v_min3_u32
      }
    }
    __syncthreads();  // next buffer staged; this buffer free
  }

  // ---- epilogue: butterfly umin over 16 lanes, threshold, store out[] ----
#pragma unroll
  for (int j = 0; j < 4; j++) {
    uint32_t bk = bestK[j];
#pragma unroll
    for (int off = 1; off < 16; off <<= 1) {
      const uint32_t ok = (uint32_t)__shfl_xor((int)bk, off);
      bk = umin2(bk, ok);
    }
    // x2 of row quad*4+j lives in the same-quad lane with col = quad*4+j
    const float x2v = __shfl(x2part, (lane & 48) + quad * 4 + j);
    if (col == 0) {
      const float Tp = __builtin_bit_cast(float, bk & 0xFFFFF000u);  // T - BIAS
      const float d2 = fmaf(-2.0f, Tp, x2v) - 2.0f * BIAS;           // x2 - 2T
      out[rowbase + quad * 4 + j] = (d2 <= 0.1f) ? (int)(bk & 4095u) : -1;
    }
  }
}

extern "C" void kernel_launch(void* const* d_in, const int* in_sizes, int n_in,
                              void* d_out, int out_size, void* d_ws, size_t ws_size,
                              hipStream_t stream) {
  const float* x = (const float*)d_in[0];      // [65536][64] fp32
  const float* codes = (const float*)d_in[1];  // [4096][64] fp32
  int* out = (int*)d_out;                      // [65536] int32

  char* ws = (char*)d_ws;
  __bf16* cb = (__bf16*)ws;                     // 512 KB
  float* nc2p = (float*)(ws + 0x080000);        // 16 KB (float2[2048])

  prep_codes_k<<<256, 256, 0, stream>>>(codes, nc2p, cb);
  nn_main<<<512, 512, 0, stream>>>(x, cb, (const float2*)nc2p, out);
}

// Round 16
// 97.990 us; speedup vs baseline: 1.0399x; 1.0399x over previous
//
#include <hip/hip_runtime.h>
#include <stdint.h>

typedef float f32x4 __attribute__((ext_vector_type(4)));
typedef __bf16 bf16x8 __attribute__((ext_vector_type(8)));
typedef __bf16 bf16x4 __attribute__((ext_vector_type(4)));

#define NROWS 65536     // 16 * 4096 x-rows
#define NCODES 4096
#define NDIM 64
#define NSPLIT 4        // code stripes (cross-block)
#define STEPS 32        // 1024 codes per stripe / 32 codes per step
#define SSTEP 2         // steps per barrier phase
#define PHASES (STEPS / SSTEP)  // 16
#define BIAS 2048.0f    // all T' = dot - c^2/2 - BIAS are < 0 (|dot| <= ~120)
#define STRIPE_BYTES 131072u
#define STRIPE_MASK 0x1FFFFu  // wrap within one stripe's 128KB

// ws layout (bytes):
//   [0x000000, 0x080000): codes bf16        4096*64*2 = 512 KB
//   [0x080000, 0x084000): nc2p paired (-||c||^2/2 - BIAS): float2[2048]
//       pair index = stripe*512 + step*16 + col ; .x = code col, .y = col+16
//   [0x100000, 0x140000): karr u32[NSPLIT][NROWS]  (packed value|code keys, 1 MB)
//   [0x300000, 0x340000): x2   float[NROWS]

__device__ __forceinline__ void gld_lds16(const void* g, void* l) {
  __builtin_amdgcn_global_load_lds(
      (const __attribute__((address_space(1))) unsigned int*)g,
      (__attribute__((address_space(3))) unsigned int*)l, 16, 0, 0);
}

__device__ __forceinline__ uint32_t umin2(uint32_t a, uint32_t b) {
  return a < b ? a : b;
}

// Coalesced prep: 65536 threads, one f32x4 each; 16 lanes per code row.
// Writes bf16 codebook + paired (-||c||^2/2 - BIAS) layout (see ws map).
__global__ __launch_bounds__(256) void prep_codes_k(const float* __restrict__ codes,
                                                    float* __restrict__ nc2p,
                                                    __bf16* __restrict__ cb) {
  const int t = blockIdx.x * 256 + threadIdx.x;  // 0..65535
  f32x4 v = *(const f32x4*)(codes + t * 4);
  bf16x4 o;
  float s = 0.f;
#pragma unroll
  for (int j = 0; j < 4; j++) {
    o[j] = (__bf16)v[j];
    s += v[j] * v[j];
  }
  *(bf16x4*)(cb + t * 4) = o;
  s += __shfl_xor(s, 1);
  s += __shfl_xor(s, 2);
  s += __shfl_xor(s, 4);
  s += __shfl_xor(s, 8);
  if ((threadIdx.x & 15) == 0) {
    const int c = t >> 4;  // code id 0..4095
    const int pidx = (c >> 10) * 512 + ((c >> 5) & 31) * 16 + (c & 15);
    const int half = (c >> 4) & 1;
    nc2p[pidx * 2 + half] = -0.5f * s - BIAS;
  }
}

// SESSION-BEST CONFIG (r12, 99.26us verified; r13/r15 alternatives regressed).
// U32-KEY ARGMAX: MFMA C-init = -c^2/2 - 2048 makes every acc value negative,
// so unsigned bit-pattern order is DESCENDING float order: umin == argmax.
// key = (bits(acc) & ~1023) | code10; lowest-code tie-break is automatic.
// Merge best=min(best,min(k0,k1)) -> v_min3_u32 (2 VALU per candidate vs 3
// for cmp+2*cndmask; argmax was 48 of ~62 VALU/step pre-r11). 10-bit
// truncation costs <=0.25 on T vs ~70 margin on the 0.1 threshold.
// PHASE ROTATION: block starts its sweep at step s0=rowgrp&31 (staging wraps
// mod 128KB) — legal since umin is visit-order independent; decorrelates
// per-phase LDS/MFMA bursts and spreads the t=0 L2 fetch over 32 tiles.
// Geometry: 2048 blocks, 4 waves share ONE 1024-code stripe via LDS
// (global_load_lds 16B/thread; B read ONCE per block per step — r6's 4x
// L2-traffic cut), 32 rows/wave, phase = 2 steps dbuf, one barrier/phase.
// Swizzle involution (rule #21): LDS[P]=G[P^(((P>>7)&7)<<4)] on store
// (P=tid*16), reader XORs the same -> identity + bank-spread ds_read_b128.
// stripe=bid>>9, rowgrp=bid&511 -> a rowgrp's 4 blocks are {r,r+512,r+1024,
// r+1536}, same XCD (mod 8) -> x slice L2-resident.
// A-frag (mfma_f32_16x16x32_bf16): lane holds A[m=lane&15][k=quad*8+j].
// C/D: col(n)=lane&15, row(m)=quad*4+reg (m89/m91-verified).
// Falsified levers (do not revisit): prefetch depth (r3), step width (r4),
// barrier freq (r7), TLP up/down (r8/r10/r13), 8-wave rebalance (r15),
// in-kernel __threadfence finalize (r9: XCD L2 writeback, 3x regression).
__global__ __launch_bounds__(256, 6) void nn_main(const float* __restrict__ x,
                                                  const __bf16* __restrict__ cbv,
                                                  const float2* __restrict__ nc2p,
                                                  uint32_t* __restrict__ karr,
                                                  float* __restrict__ x2arr) {
  const int tid  = threadIdx.x;
  const int lane = tid & 63;
  const int w    = tid >> 6;   // wave id = row chunk
  const int col  = lane & 15;
  const int quad = lane >> 4;
  const int stripe = blockIdx.x >> 9;      // 0..3
  const int rowgrp = blockIdx.x & 511;     // 0..511
  const int rowbase = rowgrp * 128 + w * 32;
  const int s0 = rowgrp & 31;              // phase-rotation start step
  const char* cbb = (const char*)cbv;

  __shared__ __align__(16) char stage[2][SSTEP * 4096];  // 16 KB
  __shared__ __align__(8) float2 ncl[512];               // 4 KB: [step][col]

  // ---- stage this stripe's nc2 pairs (4 KB) + rotated phase 0 (8 KB) ----
  const uint32_t schunk = ((uint32_t)(tid * 16)) ^ ((((uint32_t)tid >> 3) & 7u) << 4);
  const char* srcbase = cbb + (uint32_t)stripe * STRIPE_BYTES + schunk;
  const uint32_t rot = (uint32_t)s0 * 4096u;
  gld_lds16((const char*)nc2p + stripe * 4096 + tid * 16, (char*)ncl + w * 1024);
#pragma unroll
  for (int i = 0; i < SSTEP; i++)
    gld_lds16(srcbase + ((rot + i * 4096u) & STRIPE_MASK),
              &stage[0][i * 4096 + w * 1024]);

  // ---- A fragments (fp32 -> bf16) + ||x||^2 (overlaps with stages) ----
  bf16x8 a[2][2];
  float x2part[2];
#pragma unroll
  for (int rt = 0; rt < 2; rt++) {
    const float* xr = x + (rowbase + rt * 16 + col) * NDIM + quad * 8;
    float p = 0.f;
#pragma unroll
    for (int kc = 0; kc < 2; kc++) {
      f32x4 v0 = *(const f32x4*)(xr + kc * 32);
      f32x4 v1 = *(const f32x4*)(xr + kc * 32 + 4);
      bf16x8 af;
#pragma unroll
      for (int j = 0; j < 4; j++) {
        af[j]     = (__bf16)v0[j];
        af[j + 4] = (__bf16)v1[j];
        p += v0[j] * v0[j] + v1[j] * v1[j];
      }
      a[rt][kc] = af;
    }
    x2part[rt] = p;
  }
#pragma unroll
  for (int rt = 0; rt < 2; rt++) {
    float p = x2part[rt];
    p += __shfl_xor(p, 16);
    p += __shfl_xor(p, 32);
    x2part[rt] = p;
  }
  if (stripe == 0 && quad == 0) {
#pragma unroll
    for (int rt = 0; rt < 2; rt++) x2arr[rowbase + rt * 16 + col] = x2part[rt];
  }

  uint32_t bestK[2][4];
#pragma unroll
  for (int rt = 0; rt < 2; rt++)
#pragma unroll
    for (int j = 0; j < 4; j++) bestK[rt][j] = 0xFFFFFFFFu;

  // ---- reader LDS byte offsets (swizzled), within a 4KB tile ----
  const uint32_t swz = ((uint32_t)(col & 7)) << 4;
  const uint32_t o00 = ((uint32_t)(col * 128 + quad * 16)) ^ swz;
  const uint32_t o01 = ((uint32_t)(col * 128 + 64 + quad * 16)) ^ swz;
  const uint32_t o10 = ((uint32_t)(2048 + col * 128 + quad * 16)) ^ swz;
  const uint32_t o11 = ((uint32_t)(2048 + col * 128 + 64 + quad * 16)) ^ swz;

  __syncthreads();  // ncl + phase 0 staged

#pragma unroll 1
  for (int p = 0; p < PHASES; ++p) {
    // prefetch next phase into the other buffer (wrapped rotated offsets)
    if (p < PHASES - 1) {
      const uint32_t pb = rot + (uint32_t)(p + 1) * (SSTEP * 4096u);
      char* dst = &stage[(p + 1) & 1][w * 1024];
#pragma unroll
      for (int i = 0; i < SSTEP; i++)
        gld_lds16(srcbase + ((pb + i * 4096u) & STRIPE_MASK), dst + i * 4096);
    }
    const char* sb = stage[p & 1];
#pragma unroll
    for (int ss = 0; ss < SSTEP; ss++) {
      const int s_eff = (s0 + p * SSTEP + ss) & 31;  // rotated step 0..31
      const float2 nv = ncl[s_eff * 16 + col];
      bf16x8 b00 = *(const bf16x8*)(sb + ss * 4096 + o00);
      bf16x8 b01 = *(const bf16x8*)(sb + ss * 4096 + o01);
      bf16x8 b10 = *(const bf16x8*)(sb + ss * 4096 + o10);
      bf16x8 b11 = *(const bf16x8*)(sb + ss * 4096 + o11);
      f32x4 ci0 = {nv.x, nv.x, nv.x, nv.x};
      f32x4 ci1 = {nv.y, nv.y, nv.y, nv.y};
      // code-id payloads (low 10 bits of key); s_eff<<5 uniform -> SALU
      const uint32_t vk0 = (uint32_t)(col | (s_eff << 5));
      const uint32_t vk1 = vk0 | 16u;
#pragma unroll
      for (int rt = 0; rt < 2; rt++) {
        f32x4 acc0 = __builtin_amdgcn_mfma_f32_16x16x32_bf16(a[rt][0], b00, ci0, 0, 0, 0);
        acc0 = __builtin_amdgcn_mfma_f32_16x16x32_bf16(a[rt][1], b01, acc0, 0, 0, 0);
        f32x4 acc1 = __builtin_amdgcn_mfma_f32_16x16x32_bf16(a[rt][0], b10, ci1, 0, 0, 0);
        acc1 = __builtin_amdgcn_mfma_f32_16x16x32_bf16(a[rt][1], b11, acc1, 0, 0, 0);
#pragma unroll
        for (int j = 0; j < 4; j++) {
          const uint32_t k0 = (__builtin_bit_cast(uint32_t, acc0[j]) & 0xFFFFFC00u) | vk0;
          const uint32_t k1 = (__builtin_bit_cast(uint32_t, acc1[j]) & 0xFFFFFC00u) | vk1;
          // min(best, min(k0,k1)) -> v_min3_u32
          bestK[rt][j] = umin2(bestK[rt][j], umin2(k0, k1));
        }
      }
    }
    __syncthreads();  // next buffer staged; this buffer free
  }

  // ---- butterfly umin across the 16 lanes sharing each row; write key ----
#pragma unroll
  for (int rt = 0; rt < 2; rt++) {
#pragma unroll
    for (int j = 0; j < 4; j++) {
      uint32_t bk = bestK[rt][j];
#pragma unroll
      for (int off = 1; off < 16; off <<= 1) {
        const uint32_t ok = (uint32_t)__shfl_xor((int)bk, off);
        bk = umin2(bk, ok);
      }
      if (col == 0) {
        const int row = rowbase + rt * 16 + quad * 4 + j;
        karr[stripe * NROWS + row] = bk;
      }
    }
  }
}

__global__ __launch_bounds__(256) void nn_final(const uint32_t* __restrict__ karr,
                                                const float* __restrict__ x2arr,
                                                int* __restrict__ out) {
  const int row = blockIdx.x * blockDim.x + threadIdx.x;
  if (row >= NROWS) return;
  uint32_t best = karr[row];
  int bs = 0;
#pragma unroll
  for (int s = 1; s < NSPLIT; s++) {
    const uint32_t kk = karr[s * NROWS + row];
    if (kk < best) {  // strict < keeps lowest stripe on exact key ties
      best = kk;
      bs = s;
    }
  }
  const float Tp = __builtin_bit_cast(float, best & 0xFFFFFC00u);  // T - BIAS
  const float d2 = fmaf(-2.0f, Tp, x2arr[row]) - 2.0f * BIAS;      // x2 - 2T
  out[row] = (d2 <= 0.1f) ? (bs * 1024 + (int)(best & 1023u)) : -1;
}

extern "C" void kernel_launch(void* const* d_in, const int* in_sizes, int n_in,
                              void* d_out, int out_size, void* d_ws, size_t ws_size,
                              hipStream_t stream) {
  const float* x = (const float*)d_in[0];      // [65536][64] fp32
  const float* codes = (const float*)d_in[1];  // [4096][64] fp32
  int* out = (int*)d_out;                      // [65536] int32

  char* ws = (char*)d_ws;
  __bf16* cb = (__bf16*)ws;                     // 512 KB
  float* nc2p = (float*)(ws + 0x080000);        // 16 KB (float2[2048])
  uint32_t* karr = (uint32_t*)(ws + 0x100000);  // 1 MB [NSPLIT][NROWS]
  float* x2arr = (float*)(ws + 0x300000);       // 256 KB

  prep_codes_k<<<256, 256, 0, stream>>>(codes, nc2p, cb);
  nn_main<<<2048, 256, 0, stream>>>(x, cb, (const float2*)nc2p, karr, x2arr);
  nn_final<<<256, 256, 0, stream>>>(karr, x2arr, out);
}